// Round 1
// baseline (303.482 us; speedup 1.0000x reference)
//
#include <hip/hip_runtime.h>

#define NUM_CODES 1024
#define CODE_DIM  256
#define N_ROWS    32768

// output layout (floats)
#define ZQ_OFF    0
#define LOSS_OFF  8388608
#define IDX_OFF   8388609
#define CS_OFF    8421377
#define NEA_OFF   8422401
#define NORM_OFF  8684545
#define ZERO_CNT  295937     // NORM_OFF - LOSS_OFF (loss + idx + cs + nea regions)

#define EMA       0.99f
#define ONE_M_EMA 0.01f
#define EPSF      1e-6f

// ws layout (floats): [0] = n, [16..16+1024) = ||e_k||^2
#define WS_N      0
#define WS_ENORM  16

// ---------------------------------------------------------------- K0: setup
__global__ void k_setup(const float* __restrict__ emb, float* __restrict__ out,
                        float* __restrict__ ws) {
  const int b = blockIdx.x, t = threadIdx.x;
  long zi = (long)b * 256 + t;
  if (zi < ZERO_CNT) out[LOSS_OFF + zi] = 0.0f;
  if (b < NUM_CODES) {
    float v = emb[(long)b * CODE_DIM + t];
    v *= v;
    #pragma unroll
    for (int o = 32; o >= 1; o >>= 1) v += __shfl_xor(v, o);
    __shared__ float s[4];
    if ((t & 63) == 0) s[t >> 6] = v;
    __syncthreads();
    if (t == 0) ws[WS_ENORM + b] = s[0] + s[1] + s[2] + s[3];
  }
}

// ---------------------------------------------------------------- K1: main
#define BM   64     // rows per block
#define NCC  256    // codes per chunk
#define BD   32     // dims per LDS stage
#define XS_S 36     // padded stride (16B aligned, breaks power-of-2 banks)
#define ES_S 36

__launch_bounds__(256, 2)
__global__ void k_main(const float* __restrict__ z, const float* __restrict__ emb,
                       const float* __restrict__ ws, float* __restrict__ out) {
  __shared__ float Xs[BM * XS_S];
  __shared__ float Es[NCC * ES_S];
  __shared__ int   s_idx[BM];
  __shared__ float s_l[4];

  const int tid = threadIdx.x;
  const int tr  = tid >> 5;   // 0..7  -> rows tr*8 .. tr*8+7
  const int tc  = tid & 31;   // 0..31 -> codes j*32 + tc
  const int row0 = blockIdx.x * BM;

  float best[8];
  int   bidx[8];
  #pragma unroll
  for (int i = 0; i < 8; ++i) { best[i] = 3.0e38f; bidx[i] = 0; }

  for (int cc = 0; cc < NUM_CODES; cc += NCC) {
    float acc[8][8];
    #pragma unroll
    for (int i = 0; i < 8; ++i)
      #pragma unroll
      for (int j = 0; j < 8; ++j) acc[i][j] = 0.0f;

    for (int d0 = 0; d0 < CODE_DIM; d0 += BD) {
      __syncthreads();  // previous-iter LDS reads done before restage
      // stage X: 64 rows x 32 dims = 512 float4, 2/thread
      #pragma unroll
      for (int rep = 0; rep < 2; ++rep) {
        int fi = rep * 256 + tid;
        int r = fi >> 3, d4 = fi & 7;
        float4 v = *(const float4*)&z[(long)(row0 + r) * CODE_DIM + d0 + d4 * 4];
        *(float4*)&Xs[r * XS_S + d4 * 4] = v;
      }
      // stage E: 256 codes x 32 dims = 2048 float4, 8/thread
      #pragma unroll
      for (int rep = 0; rep < 8; ++rep) {
        int fi = rep * 256 + tid;
        int c = fi >> 3, d4 = fi & 7;
        float4 v = *(const float4*)&emb[(long)(cc + c) * CODE_DIM + d0 + d4 * 4];
        *(float4*)&Es[c * ES_S + d4 * 4] = v;
      }
      __syncthreads();

      #pragma unroll
      for (int dd = 0; dd < BD; dd += 4) {
        float4 xv[8], ev[8];
        #pragma unroll
        for (int i = 0; i < 8; ++i)
          xv[i] = *(const float4*)&Xs[(tr * 8 + i) * XS_S + dd];
        #pragma unroll
        for (int j = 0; j < 8; ++j)
          ev[j] = *(const float4*)&Es[(j * 32 + tc) * ES_S + dd];
        #pragma unroll
        for (int i = 0; i < 8; ++i)
          #pragma unroll
          for (int j = 0; j < 8; ++j) {
            acc[i][j] = fmaf(xv[i].x, ev[j].x, acc[i][j]);
            acc[i][j] = fmaf(xv[i].y, ev[j].y, acc[i][j]);
            acc[i][j] = fmaf(xv[i].z, ev[j].z, acc[i][j]);
            acc[i][j] = fmaf(xv[i].w, ev[j].w, acc[i][j]);
          }
      }
    }
    // fold this chunk into running argmin (ascending code order -> first-min kept)
    #pragma unroll
    for (int j = 0; j < 8; ++j) {
      int c = cc + j * 32 + tc;
      float en = ws[WS_ENORM + c];
      #pragma unroll
      for (int i = 0; i < 8; ++i) {
        float s = fmaf(-2.0f, acc[i][j], en);   // ||x||^2 shift cancels in argmin
        if (s < best[i]) { best[i] = s; bidx[i] = c; }
      }
    }
  }

  // cross-lane argmin over tc (32 lanes share the same 8 rows), idx tie-break
  #pragma unroll
  for (int i = 0; i < 8; ++i) {
    float v = best[i]; int ix = bidx[i];
    #pragma unroll
    for (int o = 16; o >= 1; o >>= 1) {
      float v2 = __shfl_xor(v, o);
      int   x2 = __shfl_xor(ix, o);
      if (v2 < v || (v2 == v && x2 < ix)) { v = v2; ix = x2; }
    }
    if (tc == 0) s_idx[tr * 8 + i] = ix;
  }
  __syncthreads();

  if (tid < BM) {
    int ix = s_idx[tid];
    out[IDX_OFF + row0 + tid] = (float)ix;
    atomicAdd(&out[CS_OFF + ix], 1.0f);
  }

  // z_q write, loss partial, embed_sum scatter
  float lacc = 0.0f;
  for (int r = 0; r < BM; ++r) {
    int ix = s_idx[r];
    long zo = (long)(row0 + r) * CODE_DIM + tid;
    float ev = emb[(long)ix * CODE_DIM + tid];
    float xv = z[zo];
    float d  = ev - xv;
    out[ZQ_OFF + zo] = xv + d;           // straight-through: zs + (zq - zs)
    lacc += d * d;
    atomicAdd(&out[NEA_OFF + (long)ix * CODE_DIM + tid], xv);
  }
  #pragma unroll
  for (int o = 32; o >= 1; o >>= 1) lacc += __shfl_xor(lacc, o);
  if ((tid & 63) == 0) s_l[tid >> 6] = lacc;
  __syncthreads();
  if (tid == 0) atomicAdd(&out[LOSS_OFF], s_l[0] + s_l[1] + s_l[2] + s_l[3]);
}

// ---------------------------------------------------------------- K2a: EMA cs + n
__global__ void k_fin1(const float* __restrict__ cs_in, float* __restrict__ out,
                       float* __restrict__ ws) {
  const int t = threadIdx.x;  // 1024 threads
  float counts = out[CS_OFF + t];
  float ncs = EMA * cs_in[t] + ONE_M_EMA * counts;
  out[CS_OFF + t] = ncs;
  float v = ncs;
  #pragma unroll
  for (int o = 32; o >= 1; o >>= 1) v += __shfl_xor(v, o);
  __shared__ float s[16];
  if ((t & 63) == 0) s[t >> 6] = v;
  __syncthreads();
  if (t == 0) {
    float n = 0.0f;
    #pragma unroll
    for (int k = 0; k < 16; ++k) n += s[k];
    ws[WS_N] = n;
  }
}

// ---------------------------------------------------------------- K2b: finalize
__global__ void k_fin2(const float* __restrict__ ea, float* __restrict__ out,
                       const float* __restrict__ ws) {
  const int k = blockIdx.x, d = threadIdx.x;
  __shared__ float s_cs;
  if (d == 0) {
    float n   = ws[WS_N];
    float ncs = out[CS_OFF + k];
    float cs  = (ncs + EPSF) / (n + (float)NUM_CODES * EPSF) * n;
    s_cs = fmaxf(cs, EPSF);
  }
  __syncthreads();
  long o = (long)k * CODE_DIM + d;
  float esum = out[NEA_OFF + o];
  float nea  = EMA * ea[o] + ONE_M_EMA * esum;
  out[NEA_OFF + o] = nea;
  out[NORM_OFF + o] = nea / s_cs;
  if (k == 0 && d == 0) out[LOSS_OFF] *= (0.25f / 8388608.0f);
}

// ---------------------------------------------------------------- launch
extern "C" void kernel_launch(void* const* d_in, const int* in_sizes, int n_in,
                              void* d_out, int out_size, void* d_ws, size_t ws_size,
                              hipStream_t stream) {
  const float* z   = (const float*)d_in[0];
  const float* emb = (const float*)d_in[1];
  const float* cs  = (const float*)d_in[2];
  const float* ea  = (const float*)d_in[3];
  float* out = (float*)d_out;
  float* ws  = (float*)d_ws;

  hipLaunchKernelGGL(k_setup, dim3(1157), dim3(256), 0, stream, emb, out, ws);
  hipLaunchKernelGGL(k_main,  dim3(N_ROWS / BM), dim3(256), 0, stream, z, emb, ws, out);
  hipLaunchKernelGGL(k_fin1,  dim3(1), dim3(1024), 0, stream, cs, out, ws);
  hipLaunchKernelGGL(k_fin2,  dim3(NUM_CODES), dim3(CODE_DIM), 0, stream, ea, out, ws);
}

// Round 2
// 148.377 us; speedup vs baseline: 2.0453x; 2.0453x over previous
//
#include <hip/hip_runtime.h>

#define NUM_CODES 1024
#define CODE_DIM  256
#define N_ROWS    32768

// output layout (floats)
#define ZQ_OFF    0
#define LOSS_OFF  8388608
#define IDX_OFF   8388609
#define CS_OFF    8421377
#define NEA_OFF   8422401
#define NORM_OFF  8684545
#define ZERO_CNT  295937     // loss + idx + cs + nea regions

#define EMA       0.99f
#define ONE_M_EMA 0.01f
#define EPSF      1e-6f

// ws layout
#define WS_N      0          // float index
#define WS_ENORM  16         // float index, 1024 floats
#define WS_EH_B   8192       // byte offset: E hi, frag-major, 512 KB
#define WS_EL_B   (8192 + 524288)  // E lo, 512 KB

typedef __attribute__((ext_vector_type(8))) short short8;
typedef __attribute__((ext_vector_type(4))) float f32x4;

__device__ __forceinline__ unsigned short f2bf(float x) {
  union { float f; unsigned u; } v; v.f = x;
  unsigned r = v.u + 0x7fffu + ((v.u >> 16) & 1u);
  return (unsigned short)(r >> 16);
}
__device__ __forceinline__ float bf2f(unsigned short b) {
  union { unsigned u; float f; } v; v.u = ((unsigned)b) << 16;
  return v.f;
}

typedef const __attribute__((address_space(1))) unsigned char* gas_t;
typedef __attribute__((address_space(3))) unsigned char* las_t;
__device__ __forceinline__ void gl_lds16(const void* g, void* l) {
  __builtin_amdgcn_global_load_lds((gas_t)g, (las_t)l, 16, 0, 0);
}

// ---------------------------------------------------------------- K0: setup
// zero accumulator regions; split E into bf16 hi/lo frag-major [plane][code][8]; enorm
__global__ void k_setup(const float* __restrict__ emb, float* __restrict__ out,
                        float* __restrict__ wsf) {
  const int b = blockIdx.x, t = threadIdx.x;
  long zi = (long)b * 256 + t;
  if (zi < ZERO_CNT) out[LOSS_OFF + zi] = 0.0f;
  if (b < NUM_CODES) {
    char* wsb = (char*)wsf;
    float x = emb[(long)b * CODE_DIM + t];
    unsigned short hb = f2bf(x);
    unsigned short lb = f2bf(x - bf2f(hb));
    unsigned short* eh = (unsigned short*)(wsb + WS_EH_B);
    unsigned short* el = (unsigned short*)(wsb + WS_EL_B);
    int p = t >> 3, j = t & 7;                 // plane = k/8, elem = k%8
    long eo = ((long)p * NUM_CODES + b) * 8 + j;
    eh[eo] = hb; el[eo] = lb;
    float v = x * x;
    #pragma unroll
    for (int o = 32; o >= 1; o >>= 1) v += __shfl_xor(v, o);
    __shared__ float s[4];
    if ((t & 63) == 0) s[t >> 6] = v;
    __syncthreads();
    if (t == 0) wsf[WS_ENORM + b] = s[0] + s[1] + s[2] + s[3];
  }
}

// ---------------------------------------------------------------- K1: main
#define BM        128        // rows per block
#define NC        32         // codes per chunk
#define NCHUNK    32
#define CHUNK_B   32768      // hi(16KB) + lo(16KB) per chunk

__launch_bounds__(512, 2)
__global__ void k_main(const float* __restrict__ z, const float* __restrict__ emb,
                       const float* __restrict__ wsf, float* __restrict__ out) {
  __shared__ __align__(16) unsigned char lds[2 * CHUNK_B];
  __shared__ int   s_idx[BM];
  __shared__ float s_l[8];

  const char* wsb = (const char*)wsf;
  const int tid = threadIdx.x;
  const int w   = tid >> 6;      // wave 0..7
  const int l   = tid & 63;
  const int mrow = l & 15;       // A-row / B-col lane field
  const int kq   = l >> 4;       // k-quarter 0..3
  const int row0 = blockIdx.x * BM;
  const long arow = row0 + w * 16 + mrow;

  // ---- load this wave's 16 X rows as hi/lo bf16 fragments (registers only)
  short8 aH[8], aL[8];
  const float* zr = z + arow * CODE_DIM + kq * 8;
  #pragma unroll
  for (int ks = 0; ks < 8; ++ks) {
    float4 f0 = *(const float4*)(zr + ks * 32);
    float4 f1 = *(const float4*)(zr + ks * 32 + 4);
    float xs[8] = {f0.x, f0.y, f0.z, f0.w, f1.x, f1.y, f1.z, f1.w};
    #pragma unroll
    for (int j = 0; j < 8; ++j) {
      unsigned short hb = f2bf(xs[j]);
      aH[ks][j] = (short)hb;
      aL[ks][j] = (short)f2bf(xs[j] - bf2f(hb));
    }
  }

  // ---- E chunk staging: global frag-major -> linear LDS (no swizzle needed)
  auto stage = [&](int chunk, int buf) {
    #pragma unroll
    for (int it = 0; it < 4; ++it) {
      int d  = (it * 512 + tid) * 16;      // 0..32752
      int s  = d >> 14;                    // 0 = hi, 1 = lo
      int d2 = d & 16383;
      int p  = d2 >> 9;                    // plane 0..31
      int in_ = d2 & 511;                  // 32 codes * 16B
      const char* src = wsb + (s ? WS_EL_B : WS_EH_B) + p * 16384 + chunk * 512 + in_;
      gl_lds16(src, (void*)(lds + buf * CHUNK_B + d));
    }
  };

  float best[4]; int bidx[4];
  #pragma unroll
  for (int r = 0; r < 4; ++r) { best[r] = 3.0e38f; bidx[r] = 0; }

  stage(0, 0);
  for (int c = 0; c < NCHUNK; ++c) {
    __syncthreads();                       // chunk c resident; prev buf free
    if (c + 1 < NCHUNK) stage(c + 1, (c + 1) & 1);
    const unsigned char* base = lds + (c & 1) * CHUNK_B;
    #pragma unroll
    for (int nt = 0; nt < 2; ++nt) {
      f32x4 acc = {0.f, 0.f, 0.f, 0.f};
      const int ci = nt * 16 + mrow;       // B col within chunk
      #pragma unroll
      for (int ks = 0; ks < 8; ++ks) {
        const int p = ks * 4 + kq;
        short8 bh = *(const short8*)(base + (p * NC + ci) * 16);
        short8 bl = *(const short8*)(base + 16384 + (p * NC + ci) * 16);
        acc = __builtin_amdgcn_mfma_f32_16x16x32_bf16(aH[ks], bh, acc, 0, 0, 0);
        acc = __builtin_amdgcn_mfma_f32_16x16x32_bf16(aH[ks], bl, acc, 0, 0, 0);
        acc = __builtin_amdgcn_mfma_f32_16x16x32_bf16(aL[ks], bh, acc, 0, 0, 0);
      }
      const int code = c * NC + nt * 16 + mrow;
      const float en = wsf[WS_ENORM + code];
      #pragma unroll
      for (int r = 0; r < 4; ++r) {
        float sv = fmaf(-2.0f, acc[r], en);    // ||x||^2 cancels in argmin
        if (sv < best[r]) { best[r] = sv; bidx[r] = code; }
      }
    }
  }

  // cross-lane argmin over the 16 lanes sharing rows (l&15 field), idx tie-break
  #pragma unroll
  for (int r = 0; r < 4; ++r) {
    float v = best[r]; int ix = bidx[r];
    #pragma unroll
    for (int o = 1; o < 16; o <<= 1) {
      float v2 = __shfl_xor(v, o);
      int   x2 = __shfl_xor(ix, o);
      if (v2 < v || (v2 == v && x2 < ix)) { v = v2; ix = x2; }
    }
    if (mrow == 0) s_idx[w * 16 + kq * 4 + r] = ix;
  }
  __syncthreads();

  if (tid < BM) {
    int ix = s_idx[tid];
    out[IDX_OFF + row0 + tid] = (float)ix;
    atomicAdd(&out[CS_OFF + ix], 1.0f);
  }

  // ---- epilogue: z_q, loss, embed_sum scatter (2 rows in parallel)
  float lacc = 0.0f;
  const int half = tid >> 8;     // 0/1
  const int d    = tid & 255;
  for (int rr = 0; rr < 64; ++rr) {
    int r  = rr * 2 + half;
    int ix = s_idx[r];
    long zo = (long)(row0 + r) * CODE_DIM + d;
    float ev = emb[(long)ix * CODE_DIM + d];
    float xv = z[zo];
    float df = ev - xv;
    out[ZQ_OFF + zo] = xv + df;            // zs + (zq - zs), matches ref rounding
    lacc += df * df;
    atomicAdd(&out[NEA_OFF + (long)ix * CODE_DIM + d], xv);
  }
  #pragma unroll
  for (int o = 32; o >= 1; o >>= 1) lacc += __shfl_xor(lacc, o);
  if (l == 0) s_l[w] = lacc;
  __syncthreads();
  if (tid == 0) {
    float t = 0.f;
    #pragma unroll
    for (int k = 0; k < 8; ++k) t += s_l[k];
    atomicAdd(&out[LOSS_OFF], t);
  }
}

// ---------------------------------------------------------------- K2a: EMA cs + n
__global__ void k_fin1(const float* __restrict__ cs_in, float* __restrict__ out,
                       float* __restrict__ wsf) {
  const int t = threadIdx.x;  // 1024 threads
  float counts = out[CS_OFF + t];
  float ncs = EMA * cs_in[t] + ONE_M_EMA * counts;
  out[CS_OFF + t] = ncs;
  float v = ncs;
  #pragma unroll
  for (int o = 32; o >= 1; o >>= 1) v += __shfl_xor(v, o);
  __shared__ float s[16];
  if ((t & 63) == 0) s[t >> 6] = v;
  __syncthreads();
  if (t == 0) {
    float n = 0.0f;
    #pragma unroll
    for (int k = 0; k < 16; ++k) n += s[k];
    wsf[WS_N] = n;
  }
}

// ---------------------------------------------------------------- K2b: finalize
__global__ void k_fin2(const float* __restrict__ ea, float* __restrict__ out,
                       const float* __restrict__ wsf) {
  const int k = blockIdx.x, d = threadIdx.x;
  __shared__ float s_cs;
  if (d == 0) {
    float n   = wsf[WS_N];
    float ncs = out[CS_OFF + k];
    float cs  = (ncs + EPSF) / (n + (float)NUM_CODES * EPSF) * n;
    s_cs = fmaxf(cs, EPSF);
  }
  __syncthreads();
  long o = (long)k * CODE_DIM + d;
  float esum = out[NEA_OFF + o];
  float nea  = EMA * ea[o] + ONE_M_EMA * esum;
  out[NEA_OFF + o] = nea;
  out[NORM_OFF + o] = nea / s_cs;
  if (k == 0 && d == 0) out[LOSS_OFF] *= (0.25f / 8388608.0f);
}

// ---------------------------------------------------------------- launch
extern "C" void kernel_launch(void* const* d_in, const int* in_sizes, int n_in,
                              void* d_out, int out_size, void* d_ws, size_t ws_size,
                              hipStream_t stream) {
  const float* z   = (const float*)d_in[0];
  const float* emb = (const float*)d_in[1];
  const float* cs  = (const float*)d_in[2];
  const float* ea  = (const float*)d_in[3];
  float* out = (float*)d_out;
  float* wsf = (float*)d_ws;

  hipLaunchKernelGGL(k_setup, dim3(1157), dim3(256), 0, stream, emb, out, wsf);
  hipLaunchKernelGGL(k_main,  dim3(N_ROWS / BM), dim3(512), 0, stream, z, emb, wsf, out);
  hipLaunchKernelGGL(k_fin1,  dim3(1), dim3(1024), 0, stream, cs, out, wsf);
  hipLaunchKernelGGL(k_fin2,  dim3(NUM_CODES), dim3(CODE_DIM), 0, stream, ea, out, wsf);
}

// Round 3
// 146.144 us; speedup vs baseline: 2.0766x; 1.0153x over previous
//
#include <hip/hip_runtime.h>

#define NUM_CODES 1024
#define CODE_DIM  256
#define N_ROWS    32768

// output layout (floats)
#define ZQ_OFF    0
#define LOSS_OFF  8388608
#define IDX_OFF   8388609
#define CS_OFF    8421377
#define NEA_OFF   8422401
#define NORM_OFF  8684545
#define ZERO_CNT  295937     // loss + idx + cs + nea regions

#define EMA       0.99f
#define ONE_M_EMA 0.01f
#define EPSF      1e-6f

// ws layout
#define WS_N      0          // float index
#define WS_ENORM  16         // float index, 1024 floats
#define WS_EH_B   8192       // byte offset: E hi, frag-major, 512 KB
#define WS_EL_B   (8192 + 524288)  // E lo, 512 KB

typedef __attribute__((ext_vector_type(8))) short short8;
typedef __attribute__((ext_vector_type(4))) float f32x4;

__device__ __forceinline__ unsigned short f2bf(float x) {
  union { float f; unsigned u; } v; v.f = x;
  unsigned r = v.u + 0x7fffu + ((v.u >> 16) & 1u);
  return (unsigned short)(r >> 16);
}
__device__ __forceinline__ float bf2f(unsigned short b) {
  union { unsigned u; float f; } v; v.u = ((unsigned)b) << 16;
  return v.f;
}

typedef const __attribute__((address_space(1))) unsigned char* gas_t;
typedef __attribute__((address_space(3))) unsigned char* las_t;
__device__ __forceinline__ void gl_lds16(const void* g, void* l) {
  __builtin_amdgcn_global_load_lds((gas_t)g, (las_t)l, 16, 0, 0);
}

// ---------------------------------------------------------------- K0: setup
// zero accumulator regions; split E into bf16 hi/lo frag-major [plane][code][8]; enorm
__global__ void k_setup(const float* __restrict__ emb, float* __restrict__ out,
                        float* __restrict__ wsf) {
  const int b = blockIdx.x, t = threadIdx.x;
  long zi = (long)b * 256 + t;
  if (zi < ZERO_CNT) out[LOSS_OFF + zi] = 0.0f;
  if (b < NUM_CODES) {
    char* wsb = (char*)wsf;
    float x = emb[(long)b * CODE_DIM + t];
    unsigned short hb = f2bf(x);
    unsigned short lb = f2bf(x - bf2f(hb));
    unsigned short* eh = (unsigned short*)(wsb + WS_EH_B);
    unsigned short* el = (unsigned short*)(wsb + WS_EL_B);
    int p = t >> 3, j = t & 7;                 // plane = k/8, elem = k%8
    long eo = ((long)p * NUM_CODES + b) * 8 + j;
    eh[eo] = hb; el[eo] = lb;
    float v = x * x;
    #pragma unroll
    for (int o = 32; o >= 1; o >>= 1) v += __shfl_xor(v, o);
    __shared__ float s[4];
    if ((t & 63) == 0) s[t >> 6] = v;
    __syncthreads();
    if (t == 0) wsf[WS_ENORM + b] = s[0] + s[1] + s[2] + s[3];
  }
}

// ---------------------------------------------------------------- K1: main
#define BM        64         // rows per block (4 waves x 16 rows)
#define NC        32         // codes per chunk
#define NCHUNK    32
#define CHUNK_B   32768      // hi(16KB) + lo(16KB) per chunk

__launch_bounds__(256, 2)
__global__ void k_main(const float* __restrict__ z, const float* __restrict__ emb,
                       const float* __restrict__ wsf, float* __restrict__ out) {
  __shared__ __align__(16) unsigned char lds[2 * CHUNK_B];
  __shared__ int   s_idx[BM];
  __shared__ float s_l[4];

  const char* wsb = (const char*)wsf;
  const int tid = threadIdx.x;
  const int w   = tid >> 6;      // wave 0..3
  const int l   = tid & 63;
  const int mrow = l & 15;       // A-row / B-col lane field
  const int kq   = l >> 4;       // k-quarter 0..3
  const int row0 = blockIdx.x * BM;
  const long arow = row0 + w * 16 + mrow;

  // ---- load this wave's 16 X rows as hi/lo bf16 fragments (registers only)
  short8 aH[8], aL[8];
  const float* zr = z + arow * CODE_DIM + kq * 8;
  #pragma unroll
  for (int ks = 0; ks < 8; ++ks) {
    float4 f0 = *(const float4*)(zr + ks * 32);
    float4 f1 = *(const float4*)(zr + ks * 32 + 4);
    float xs[8] = {f0.x, f0.y, f0.z, f0.w, f1.x, f1.y, f1.z, f1.w};
    #pragma unroll
    for (int j = 0; j < 8; ++j) {
      unsigned short hb = f2bf(xs[j]);
      aH[ks][j] = (short)hb;
      aL[ks][j] = (short)f2bf(xs[j] - bf2f(hb));
    }
  }

  // ---- E chunk staging: global frag-major -> linear LDS (no swizzle needed)
  auto stage = [&](int chunk, int buf) {
    #pragma unroll
    for (int it = 0; it < 8; ++it) {
      int d  = (it * 256 + tid) * 16;      // 0..32752
      int s  = d >> 14;                    // 0 = hi, 1 = lo
      int d2 = d & 16383;
      int p  = d2 >> 9;                    // plane 0..31
      int in_ = d2 & 511;                  // 32 codes * 16B
      const char* src = wsb + (s ? WS_EL_B : WS_EH_B) + p * 16384 + chunk * 512 + in_;
      gl_lds16(src, (void*)(lds + buf * CHUNK_B + d));
    }
  };

  float best[4]; int bidx[4];
  #pragma unroll
  for (int r = 0; r < 4; ++r) { best[r] = 3.0e38f; bidx[r] = 0; }

  stage(0, 0);
  for (int c = 0; c < NCHUNK; ++c) {
    __syncthreads();                       // chunk c resident; prev buf free
    if (c + 1 < NCHUNK) stage(c + 1, (c + 1) & 1);
    const unsigned char* base = lds + (c & 1) * CHUNK_B;
    #pragma unroll
    for (int nt = 0; nt < 2; ++nt) {
      // 3 independent accumulator chains (hh / lh / hl) -> 6 chains in flight
      f32x4 accA = {0.f, 0.f, 0.f, 0.f};
      f32x4 accB = {0.f, 0.f, 0.f, 0.f};
      f32x4 accC = {0.f, 0.f, 0.f, 0.f};
      const int ci = nt * 16 + mrow;       // B col within chunk
      #pragma unroll
      for (int ks = 0; ks < 8; ++ks) {
        const int p = ks * 4 + kq;
        short8 bh = *(const short8*)(base + (p * NC + ci) * 16);
        short8 bl = *(const short8*)(base + 16384 + (p * NC + ci) * 16);
        accA = __builtin_amdgcn_mfma_f32_16x16x32_bf16(aH[ks], bh, accA, 0, 0, 0);
        accB = __builtin_amdgcn_mfma_f32_16x16x32_bf16(aL[ks], bh, accB, 0, 0, 0);
        accC = __builtin_amdgcn_mfma_f32_16x16x32_bf16(aH[ks], bl, accC, 0, 0, 0);
      }
      const int code = c * NC + nt * 16 + mrow;
      const float en = wsf[WS_ENORM + code];
      #pragma unroll
      for (int r = 0; r < 4; ++r) {
        float dot = accA[r] + accB[r] + accC[r];
        float sv = fmaf(-2.0f, dot, en);     // ||x||^2 cancels in argmin
        if (sv < best[r]) { best[r] = sv; bidx[r] = code; }
      }
    }
  }

  // cross-lane argmin over the 16 lanes sharing rows (l&15 field), idx tie-break
  #pragma unroll
  for (int r = 0; r < 4; ++r) {
    float v = best[r]; int ix = bidx[r];
    #pragma unroll
    for (int o = 1; o < 16; o <<= 1) {
      float v2 = __shfl_xor(v, o);
      int   x2 = __shfl_xor(ix, o);
      if (v2 < v || (v2 == v && x2 < ix)) { v = v2; ix = x2; }
    }
    if (mrow == 0) s_idx[w * 16 + kq * 4 + r] = ix;
  }
  __syncthreads();

  if (tid < BM) {
    int ix = s_idx[tid];
    out[IDX_OFF + row0 + tid] = (float)ix;
    atomicAdd(&out[CS_OFF + ix], 1.0f);
  }

  // ---- epilogue: z_q, loss, embed_sum scatter (thread tid owns dim d=tid)
  float lacc = 0.0f;
  for (int r = 0; r < BM; ++r) {
    int ix = s_idx[r];
    long zo = (long)(row0 + r) * CODE_DIM + tid;
    float ev = emb[(long)ix * CODE_DIM + tid];
    float xv = z[zo];
    float df = ev - xv;
    out[ZQ_OFF + zo] = xv + df;            // zs + (zq - zs), matches ref rounding
    lacc += df * df;
    atomicAdd(&out[NEA_OFF + (long)ix * CODE_DIM + tid], xv);
  }
  #pragma unroll
  for (int o = 32; o >= 1; o >>= 1) lacc += __shfl_xor(lacc, o);
  if (l == 0) s_l[w] = lacc;
  __syncthreads();
  if (tid == 0) {
    float t = 0.f;
    #pragma unroll
    for (int k = 0; k < 4; ++k) t += s_l[k];
    atomicAdd(&out[LOSS_OFF], t);
  }
}

// ---------------------------------------------------------------- K2a: EMA cs + n
__global__ void k_fin1(const float* __restrict__ cs_in, float* __restrict__ out,
                       float* __restrict__ wsf) {
  const int t = threadIdx.x;  // 1024 threads
  float counts = out[CS_OFF + t];
  float ncs = EMA * cs_in[t] + ONE_M_EMA * counts;
  out[CS_OFF + t] = ncs;
  float v = ncs;
  #pragma unroll
  for (int o = 32; o >= 1; o >>= 1) v += __shfl_xor(v, o);
  __shared__ float s[16];
  if ((t & 63) == 0) s[t >> 6] = v;
  __syncthreads();
  if (t == 0) {
    float n = 0.0f;
    #pragma unroll
    for (int k = 0; k < 16; ++k) n += s[k];
    wsf[WS_N] = n;
  }
}

// ---------------------------------------------------------------- K2b: finalize
__global__ void k_fin2(const float* __restrict__ ea, float* __restrict__ out,
                       const float* __restrict__ wsf) {
  const int k = blockIdx.x, d = threadIdx.x;
  __shared__ float s_cs;
  if (d == 0) {
    float n   = wsf[WS_N];
    float ncs = out[CS_OFF + k];
    float cs  = (ncs + EPSF) / (n + (float)NUM_CODES * EPSF) * n;
    s_cs = fmaxf(cs, EPSF);
  }
  __syncthreads();
  long o = (long)k * CODE_DIM + d;
  float esum = out[NEA_OFF + o];
  float nea  = EMA * ea[o] + ONE_M_EMA * esum;
  out[NEA_OFF + o] = nea;
  out[NORM_OFF + o] = nea / s_cs;
  if (k == 0 && d == 0) out[LOSS_OFF] *= (0.25f / 8388608.0f);
}

// ---------------------------------------------------------------- launch
extern "C" void kernel_launch(void* const* d_in, const int* in_sizes, int n_in,
                              void* d_out, int out_size, void* d_ws, size_t ws_size,
                              hipStream_t stream) {
  const float* z   = (const float*)d_in[0];
  const float* emb = (const float*)d_in[1];
  const float* cs  = (const float*)d_in[2];
  const float* ea  = (const float*)d_in[3];
  float* out = (float*)d_out;
  float* wsf = (float*)d_ws;

  hipLaunchKernelGGL(k_setup, dim3(1157), dim3(256), 0, stream, emb, out, wsf);
  hipLaunchKernelGGL(k_main,  dim3(N_ROWS / BM), dim3(256), 0, stream, z, emb, wsf, out);
  hipLaunchKernelGGL(k_fin1,  dim3(1), dim3(1024), 0, stream, cs, out, wsf);
  hipLaunchKernelGGL(k_fin2,  dim3(NUM_CODES), dim3(CODE_DIM), 0, stream, ea, out, wsf);
}